// Round 1
// baseline (729.096 us; speedup 1.0000x reference)
//
#include <hip/hip_runtime.h>

#define N_NODES 80000
#define N_EDGES 1280000
#define IN_CH 128
#define HID 64
#define OUT_CH 32

// ---------------- degree / dinv ----------------
__global__ void k_deg_init(int* __restrict__ deg) {
    int i = blockIdx.x * blockDim.x + threadIdx.x;
    if (i < N_NODES) deg[i] = 1;  // self loop
}

__global__ void k_deg_count(const int* __restrict__ dst, int* __restrict__ deg) {
    int e = blockIdx.x * blockDim.x + threadIdx.x;
    if (e < N_EDGES) atomicAdd(&deg[dst[e]], 1);
}

__global__ void k_dinv(const int* __restrict__ deg, float* __restrict__ dinv) {
    int i = blockIdx.x * blockDim.x + threadIdx.x;
    if (i < N_NODES) dinv[i] = rsqrtf((float)deg[i]);
}

// ---------------- layer GEMMs (pre-scaled by dinv[src]) ----------------
// g1[n][f] = dinv[n] * sum_k x[n][k] * W1[k][f]   (F=64)
__global__ __launch_bounds__(256) void k_gemm1(const float* __restrict__ x,
                                               const float* __restrict__ W1,
                                               const float* __restrict__ dinv,
                                               float* __restrict__ g1) {
    __shared__ float sW[IN_CH * HID];  // 32 KB
    for (int i = threadIdx.x; i < IN_CH * HID; i += 256) sW[i] = W1[i];
    __syncthreads();
    int f = threadIdx.x & 63;
    int n = blockIdx.x * 4 + (threadIdx.x >> 6);
    if (n >= N_NODES) return;
    const float* xr = x + (long long)n * IN_CH;
    float acc = 0.f;
#pragma unroll 8
    for (int k = 0; k < IN_CH; ++k) acc += xr[k] * sW[k * HID + f];
    g1[(long long)n * HID + f] = acc * dinv[n];
}

// g2[n][f] = dinv[n] * sum_k h2[n][k] * W2[k][f]   (F=32)
__global__ __launch_bounds__(256) void k_gemm2(const float* __restrict__ h2,
                                               const float* __restrict__ W2,
                                               const float* __restrict__ dinv,
                                               float* __restrict__ g2) {
    __shared__ float sW[HID * OUT_CH];  // 8 KB
    for (int i = threadIdx.x; i < HID * OUT_CH; i += 256) sW[i] = W2[i];
    __syncthreads();
    int f = threadIdx.x & 31;
    int n = blockIdx.x * 8 + (threadIdx.x >> 5);
    if (n >= N_NODES) return;
    const float* hr = h2 + (long long)n * HID;
    float acc = 0.f;
#pragma unroll 8
    for (int k = 0; k < HID; ++k) acc += hr[k] * sW[k * OUT_CH + f];
    g2[(long long)n * OUT_CH + f] = acc * dinv[n];
}

// ---------------- edge scatter-add (atomics) ----------------
template <int F>
__global__ __launch_bounds__(256) void k_scatter(const int* __restrict__ src,
                                                 const int* __restrict__ dst,
                                                 const float* __restrict__ g,
                                                 float* __restrict__ agg) {
    long long t = (long long)blockIdx.x * blockDim.x + threadIdx.x;
    if (t >= (long long)N_EDGES * F) return;
    int e = (int)(t / F);
    int f = (int)(t % F);
    atomicAdd(&agg[(long long)dst[e] * F + f], g[(long long)src[e] * F + f]);
}

// ---------------- epilogues ----------------
// h2 = relu(dinv[n]*(aggE + g1) + b1)   written in-place over aggE
__global__ void k_finalize1(const float* __restrict__ g1, float* __restrict__ agg1,
                            const float* __restrict__ dinv, const float* __restrict__ b1) {
    int t = blockIdx.x * blockDim.x + threadIdx.x;
    if (t >= N_NODES * HID) return;
    int n = t >> 6, f = t & 63;
    float v = dinv[n] * (agg1[t] + g1[t]) + b1[f];
    agg1[t] = v > 0.f ? v : 0.f;
}

__global__ void k_finalize2(const float* __restrict__ g2, const float* __restrict__ agg2,
                            const float* __restrict__ dinv, const float* __restrict__ b2,
                            float* __restrict__ out) {
    int t = blockIdx.x * blockDim.x + threadIdx.x;
    if (t >= N_NODES * OUT_CH) return;
    int n = t >> 5, f = t & 31;
    out[t] = dinv[n] * (agg2[t] + g2[t]) + b2[f];
}

extern "C" void kernel_launch(void* const* d_in, const int* in_sizes, int n_in,
                              void* d_out, int out_size, void* d_ws, size_t ws_size,
                              hipStream_t stream) {
    const float* x  = (const float*)d_in[0];
    const int*   ei = (const int*)d_in[1];
    const float* W1 = (const float*)d_in[2];
    const float* b1 = (const float*)d_in[3];
    const float* W2 = (const float*)d_in[4];
    const float* b2 = (const float*)d_in[5];
    float* out = (float*)d_out;

    const int* src = ei;
    const int* dst = ei + N_EDGES;

    // workspace layout (bytes):
    //  deg  : N int                       [0, 4N)
    //  dinv : N float                     [4N, 8N)
    //  g1   : 64N float                   [8N, 8N+256N)
    //  agg1 : 64N float (becomes h2)      [8N+256N, 8N+512N)
    // layer2 reuses g1's region: g2 = first 32N floats, agg2 = next 32N floats
    char* ws = (char*)d_ws;
    int*   deg  = (int*)ws;
    float* dinv = (float*)(ws + (size_t)N_NODES * 4);
    float* g1   = (float*)(ws + (size_t)N_NODES * 8);
    float* agg1 = g1 + (size_t)N_NODES * HID;   // later: h2 (in-place)
    float* g2   = g1;                            // reuse
    float* agg2 = g1 + (size_t)N_NODES * OUT_CH; // reuse

    // --- degrees ---
    k_deg_init<<<(N_NODES + 255) / 256, 256, 0, stream>>>(deg);
    k_deg_count<<<(N_EDGES + 255) / 256, 256, 0, stream>>>(dst, deg);
    k_dinv<<<(N_NODES + 255) / 256, 256, 0, stream>>>(deg, dinv);

    // --- layer 1 ---
    hipMemsetAsync(agg1, 0, (size_t)N_NODES * HID * 4, stream);
    k_gemm1<<<N_NODES / 4, 256, 0, stream>>>(x, W1, dinv, g1);
    {
        long long total = (long long)N_EDGES * HID;
        int blocks = (int)((total + 255) / 256);
        k_scatter<HID><<<blocks, 256, 0, stream>>>(src, dst, g1, agg1);
    }
    k_finalize1<<<(N_NODES * HID + 255) / 256, 256, 0, stream>>>(g1, agg1, dinv, b1);
    // agg1 now holds h2 [N, 64]

    // --- layer 2 ---
    hipMemsetAsync(agg2, 0, (size_t)N_NODES * OUT_CH * 4, stream);
    k_gemm2<<<N_NODES / 8, 256, 0, stream>>>(agg1, W2, dinv, g2);
    {
        long long total = (long long)N_EDGES * OUT_CH;
        int blocks = (int)((total + 255) / 256);
        k_scatter<OUT_CH><<<blocks, 256, 0, stream>>>(src, dst, g2, agg2);
    }
    k_finalize2<<<(N_NODES * OUT_CH + 255) / 256, 256, 0, stream>>>(g2, agg2, dinv, b2, out);
}

// Round 2
// 412.970 us; speedup vs baseline: 1.7655x; 1.7655x over previous
//
#include <hip/hip_runtime.h>

#define N_NODES 80000
#define N_EDGES 1280000
#define IN_CH 128
#define HID 64
#define OUT_CH 32
#define NBLK 313  // ceil(80000/256)

// ---------------- degree / dinv ----------------
__global__ void k_deg_init(int* __restrict__ deg) {
    int i = blockIdx.x * blockDim.x + threadIdx.x;
    if (i < N_NODES) deg[i] = 1;  // self loop
}

__global__ void k_deg_count(const int* __restrict__ dst, int* __restrict__ deg) {
    int e = blockIdx.x * blockDim.x + threadIdx.x;
    if (e < N_EDGES) atomicAdd(&deg[dst[e]], 1);
}

__global__ void k_dinv(const int* __restrict__ deg, float* __restrict__ dinv) {
    int i = blockIdx.x * blockDim.x + threadIdx.x;
    if (i < N_NODES) dinv[i] = rsqrtf((float)deg[i]);
}

// ---------------- 3-pass exclusive scan of (deg-1) -> row_start ----------------
__global__ void k_scan_a(const int* __restrict__ deg, int* __restrict__ bsum) {
    __shared__ int s[256];
    int t = threadIdx.x;
    int i = blockIdx.x * 256 + t;
    s[t] = (i < N_NODES) ? deg[i] - 1 : 0;
    __syncthreads();
    for (int off = 128; off; off >>= 1) {
        if (t < off) s[t] += s[t + off];
        __syncthreads();
    }
    if (t == 0) bsum[blockIdx.x] = s[0];
}

__global__ void k_scan_b(const int* __restrict__ bsum, int* __restrict__ bpre) {
    __shared__ int s[512];
    int t = threadIdx.x;
    int v = (t < NBLK) ? bsum[t] : 0;
    s[t] = v;
    __syncthreads();
    for (int off = 1; off < 512; off <<= 1) {
        int add = (t >= off) ? s[t - off] : 0;
        __syncthreads();
        s[t] += add;
        __syncthreads();
    }
    bpre[t] = s[t] - v;  // exclusive
}

__global__ void k_scan_c(const int* __restrict__ deg, const int* __restrict__ bpre,
                         int* __restrict__ row_start, int* __restrict__ cursor) {
    __shared__ int s[256];
    int t = threadIdx.x;
    int i = blockIdx.x * 256 + t;
    int v = (i < N_NODES) ? deg[i] - 1 : 0;
    s[t] = v;
    __syncthreads();
    for (int off = 1; off < 256; off <<= 1) {
        int add = (t >= off) ? s[t - off] : 0;
        __syncthreads();
        s[t] += add;
        __syncthreads();
    }
    if (i < N_NODES) {
        int rs = bpre[blockIdx.x] + s[t] - v;
        row_start[i] = rs;
        cursor[i] = rs;
    }
    if (i == 0) row_start[N_NODES] = N_EDGES;
}

// ---------------- CSR fill ----------------
__global__ void k_fill(const int* __restrict__ src, const int* __restrict__ dst,
                       int* __restrict__ cursor, int* __restrict__ csr_src) {
    int e = blockIdx.x * blockDim.x + threadIdx.x;
    if (e < N_EDGES) {
        int d = dst[e];
        int slot = atomicAdd(&cursor[d], 1);
        csr_src[slot] = src[e];
    }
}

// ---------------- GEMM1 half: g1h[n][0:32] = dinv[n] * x[n] @ W1[:, c0:c0+32] ----
__global__ __launch_bounds__(256) void k_gemm1h(const float* __restrict__ x,
                                                const float* __restrict__ W1,
                                                const float* __restrict__ dinv,
                                                float* __restrict__ g1h, int c0) {
    __shared__ float sX[64 * 132];   // 64 nodes x (128 + pad 4)
    __shared__ float sW[128 * 32];
    int t = threadIdx.x;
    long long nb = (long long)blockIdx.x * 64;
    for (int i = t * 4; i < 128 * 32; i += 1024) {
        int k = i >> 5, c = i & 31;
        *(float4*)&sW[i] = *(const float4*)&W1[k * 64 + c0 + c];
    }
    for (int r = 0; r < 8; ++r) {
        int n = (t >> 5) + r * 8;
        int k4 = (t & 31) * 4;
        *(float4*)&sX[n * 132 + k4] = *(const float4*)&x[(nb + n) * IN_CH + k4];
    }
    __syncthreads();
    int tx = t & 7, ty = t >> 3;  // f0 = tx*4, nodes ty*2, ty*2+1
    float acc0[4] = {0, 0, 0, 0}, acc1[4] = {0, 0, 0, 0};
#pragma unroll 4
    for (int k = 0; k < 128; ++k) {
        float4 w = *(float4*)&sW[k * 32 + tx * 4];
        float x0 = sX[(ty * 2 + 0) * 132 + k];
        float x1 = sX[(ty * 2 + 1) * 132 + k];
        acc0[0] += x0 * w.x; acc0[1] += x0 * w.y; acc0[2] += x0 * w.z; acc0[3] += x0 * w.w;
        acc1[0] += x1 * w.x; acc1[1] += x1 * w.y; acc1[2] += x1 * w.z; acc1[3] += x1 * w.w;
    }
#pragma unroll
    for (int j = 0; j < 2; ++j) {
        long long n = nb + ty * 2 + j;
        float dn = dinv[n];
        float* a = j ? acc1 : acc0;
        float4 o = {a[0] * dn, a[1] * dn, a[2] * dn, a[3] * dn};
        *(float4*)&g1h[n * 32 + tx * 4] = o;
    }
}

// ---------------- GEMM2: g2[n] = dinv[n] * h2[n] @ W2   (K=64, F=32) ----------
__global__ __launch_bounds__(256) void k_gemm2(const float* __restrict__ h2,
                                               const float* __restrict__ W2,
                                               const float* __restrict__ dinv,
                                               float* __restrict__ g2) {
    __shared__ float sX[64 * 68];   // 64 nodes x (64 + pad 4)
    __shared__ float sW[64 * 32];
    int t = threadIdx.x;
    long long nb = (long long)blockIdx.x * 64;
    for (int i = t * 4; i < 64 * 32; i += 1024) {
        *(float4*)&sW[i] = *(const float4*)&W2[i];
    }
    for (int r = 0; r < 4; ++r) {
        int n = (t >> 4) + r * 16;
        int k4 = (t & 15) * 4;
        *(float4*)&sX[n * 68 + k4] = *(const float4*)&h2[(nb + n) * HID + k4];
    }
    __syncthreads();
    int tx = t & 7, ty = t >> 3;
    float acc0[4] = {0, 0, 0, 0}, acc1[4] = {0, 0, 0, 0};
#pragma unroll 4
    for (int k = 0; k < 64; ++k) {
        float4 w = *(float4*)&sW[k * 32 + tx * 4];
        float x0 = sX[(ty * 2 + 0) * 68 + k];
        float x1 = sX[(ty * 2 + 1) * 68 + k];
        acc0[0] += x0 * w.x; acc0[1] += x0 * w.y; acc0[2] += x0 * w.z; acc0[3] += x0 * w.w;
        acc1[0] += x1 * w.x; acc1[1] += x1 * w.y; acc1[2] += x1 * w.z; acc1[3] += x1 * w.w;
    }
#pragma unroll
    for (int j = 0; j < 2; ++j) {
        long long n = nb + ty * 2 + j;
        float dn = dinv[n];
        float* a = j ? acc1 : acc0;
        float4 o = {a[0] * dn, a[1] * dn, a[2] * dn, a[3] * dn};
        *(float4*)&g2[n * 32 + tx * 4] = o;
    }
}

// ---------------- CSR aggregate, F=32, one wave per node -----------------------
// acc[f] = g[n][f] + sum_{e in row(n)} g[csr[e]][f]; lanes 0-31 take even edges,
// lanes 32-63 odd edges; combine via shfl. out[n*out_stride + bias_off + f] =
// relu?(dinv[n]*acc + bias[bias_off+f])
__global__ __launch_bounds__(256) void k_agg32(const float* __restrict__ g,
                                               const int* __restrict__ row_start,
                                               const int* __restrict__ csr_src,
                                               const float* __restrict__ dinv,
                                               const float* __restrict__ bias,
                                               float* __restrict__ outp,
                                               int out_stride, int bias_off, int do_relu) {
    int n = blockIdx.x * 4 + (threadIdx.x >> 6);
    int f = threadIdx.x & 63;
    int half = f >> 5, fo = f & 31;
    int rs = row_start[n], re = row_start[n + 1];
    float acc = half ? 0.f : g[(long long)n * 32 + fo];
    int e = rs + half;
    for (; e + 6 < re; e += 8) {
        int s0 = csr_src[e], s1 = csr_src[e + 2], s2 = csr_src[e + 4], s3 = csr_src[e + 6];
        float v0 = g[(long long)s0 * 32 + fo];
        float v1 = g[(long long)s1 * 32 + fo];
        float v2 = g[(long long)s2 * 32 + fo];
        float v3 = g[(long long)s3 * 32 + fo];
        acc += v0 + v1 + v2 + v3;
    }
    for (; e < re; e += 2) acc += g[(long long)csr_src[e] * 32 + fo];
    acc += __shfl_down(acc, 32);
    if (half == 0) {
        float v = dinv[n] * acc + bias[bias_off + fo];
        if (do_relu) v = fmaxf(v, 0.f);
        outp[(long long)n * out_stride + bias_off + fo] = v;
    }
}

extern "C" void kernel_launch(void* const* d_in, const int* in_sizes, int n_in,
                              void* d_out, int out_size, void* d_ws, size_t ws_size,
                              hipStream_t stream) {
    const float* x  = (const float*)d_in[0];
    const int*   ei = (const int*)d_in[1];
    const float* W1 = (const float*)d_in[2];
    const float* b1 = (const float*)d_in[3];
    const float* W2 = (const float*)d_in[4];
    const float* b2 = (const float*)d_in[5];
    float* out = (float*)d_out;

    const int* src = ei;
    const int* dst = ei + N_EDGES;

    // workspace layout (all sections 16B-aligned; peak ~37.1 MB < 41.6 MB proven in R1)
    char* ws = (char*)d_ws;
    int*   deg       = (int*)ws;                                   // 80000
    float* dinv      = (float*)(deg + N_NODES);                    // 80000
    int*   cursor    = (int*)(dinv + N_NODES);                     // 80000
    int*   bsum      = cursor + N_NODES;                           // 512
    int*   bpre      = bsum + 512;                                 // 512
    int*   row_start = bpre + 512;                                 // 80004 (padded)
    int*   csr_src   = row_start + N_NODES + 4;                    // 1280000
    float* g1h       = (float*)(csr_src + N_EDGES);                // 80000*32 (reused: g1 halves, then g2)
    float* h2        = g1h + (size_t)N_NODES * 32;                 // 80000*64

    // --- degrees + dinv ---
    k_deg_init<<<NBLK, 256, 0, stream>>>(deg);
    k_deg_count<<<N_EDGES / 256, 256, 0, stream>>>(dst, deg);
    k_dinv<<<NBLK, 256, 0, stream>>>(deg, dinv);

    // --- CSR build (by dst) ---
    k_scan_a<<<NBLK, 256, 0, stream>>>(deg, bsum);
    k_scan_b<<<1, 512, 0, stream>>>(bsum, bpre);
    k_scan_c<<<NBLK, 256, 0, stream>>>(deg, bpre, row_start, cursor);
    k_fill<<<N_EDGES / 256, 256, 0, stream>>>(src, dst, cursor, csr_src);

    // --- layer 1, feature-halves c0 = 0, 32 ---
    for (int c0 = 0; c0 < HID; c0 += 32) {
        k_gemm1h<<<N_NODES / 64, 256, 0, stream>>>(x, W1, dinv, g1h, c0);
        k_agg32<<<N_NODES / 4, 256, 0, stream>>>(g1h, row_start, csr_src, dinv, b1,
                                                 h2, HID, c0, 1);
    }

    // --- layer 2 ---
    float* g2 = g1h;  // reuse
    k_gemm2<<<N_NODES / 64, 256, 0, stream>>>(h2, W2, dinv, g2);
    k_agg32<<<N_NODES / 4, 256, 0, stream>>>(g2, row_start, csr_src, dinv, b2,
                                             out, OUT_CH, 0, 0);
}